// Round 2
// baseline (1839.678 us; speedup 1.0000x reference)
//
#include <hip/hip_runtime.h>
#include <cstdint>
#include <cstddef>

typedef __bf16 bf16;
typedef __bf16 bf16x8 __attribute__((ext_vector_type(8)));
typedef __bf16 bf16x4 __attribute__((ext_vector_type(4)));
typedef float  f32x4  __attribute__((ext_vector_type(4)));

#define D_MODEL 512
#define D_INNER 1024
#define D_STATE 16
#define D_CONV  4
#define DT_RANK 32
#define N_LAYER 4
#define H_FFN   2048
#define SEQ_T   1024
#define BATCH   2
#define BT      (BATCH * SEQ_T)   // 2048 tokens
#define VOCAB   32000

// chunked scan parameters
#define NCHUNK  16
#define CHUNK   (SEQ_T / NCHUNK)  // 64

__device__ __forceinline__ float b2f(bf16 x) { return (float)x; }
__device__ __forceinline__ bf16  f2b(float x) { return (bf16)x; }

// dual-dtype scalar read: p holds bf16 if bf!=0 else f32
__device__ __forceinline__ float rdf(const void* p, long i, int bf) {
  return bf ? (float)((const bf16*)p)[i] : ((const float*)p)[i];
}

__device__ __forceinline__ void async16(const void* g, void* l) {
  __builtin_amdgcn_global_load_lds((const __attribute__((address_space(1))) void*)g,
                                   (__attribute__((address_space(3))) void*)l, 16, 0, 0);
}

// ---------------------------------------------------------------------------
// dtype probe: if inputs are f32, bf16-view words at even indices are mantissa
// fragments -> random exponent -> some |x| >= 128 with certainty over 512
// words. Real bf16 data here is |x| <= ~0.2.  flag=1 -> inputs are bf16.
// ---------------------------------------------------------------------------
__global__ void probe_k(const unsigned short* __restrict__ tok,
                        const unsigned short* __restrict__ pos,
                        int* __restrict__ flag)
{
  int lane = threadIdx.x;
  int bad = 0;
  for (int i = lane; i < 512; i += 64) {
    int e0 = (tok[i] >> 7) & 0xFF;
    int e1 = (pos[i] >> 7) & 0xFF;
    if (e0 >= 134 || e1 >= 134) bad = 1;   // |v|>=128 or inf/nan
  }
  unsigned long long m = __ballot(bad);
  if (lane == 0) *flag = (m == 0ULL) ? 1 : 0;
}

// f32 -> bf16 arena conversion (no-op when inputs are already bf16)
__global__ __launch_bounds__(256) void cvt_k(const float4* __restrict__ src,
                                             bf16* __restrict__ dst,
                                             int n4, const int* __restrict__ dflag)
{
  if (*dflag) return;
  int i = blockIdx.x * 256 + threadIdx.x;
  if (i >= n4) return;
  float4 v = src[i];
  bf16x4 o; o[0] = f2b(v.x); o[1] = f2b(v.y); o[2] = f2b(v.z); o[3] = f2b(v.w);
  *(bf16x4*)(dst + (size_t)i * 4) = o;
}

// ---------------------------------------------------------------------------
// NT GEMM: C[M,N] = A[M,K] * B[N,K]^T. A: bf16 (internal). B: canonical bf16
// arena (flag=0) or raw d_in read as bf16 (flag=1). 128x128 tile, BK=32,
// 4 waves, mfma_f32_16x16x32_bf16, global_load_lds width-16 staging.
//
// Round-1: depth-2 software pipeline (T3/T4-minimum):
//   3 LDS buffer slots, raw s_barrier (no implicit vmcnt(0) drain),
//   counted "s_waitcnt vmcnt(8)" in steady state (2 stages x 4 loads/thread
//   in flight).  Per-iter order:
//     stage(t+2) -> vmcnt(8) -> barrier -> ds_read(t%3) -> lgkmcnt(0)
//     -> barrier -> MFMA
//   Buffer-overwrite safety: stage into slot s at iter t follows the
//   lgkmcnt(0)+barrier of iter t-1 whose ds_reads were the last readers of s.
//   vmcnt(0) drain after the loop protects LDS for the next workgroup.
//
// SWZ (logits only): bijective XCD-chunk remap, y-fastest within chunk ->
// each XCD owns a contiguous N-tile range and walks all M-tiles for it:
// B-tile fetched once per chip, A (2 MB) L2-resident.
// OUTMODE: 0=f32, 1=bf16, 2=select by flag (final logits).
// ---------------------------------------------------------------------------
template<int OUTMODE, bool RELU, bool SWZ>
__global__ __launch_bounds__(256) void gemm_nt(
    const bf16* __restrict__ A, const bf16* __restrict__ Barena,
    const void* __restrict__ Braw, long boff,
    void* __restrict__ Cout, const void* __restrict__ bias, long biasoff,
    const float* __restrict__ res, const int* __restrict__ dflag,
    int M, int N, int K)
{
  __shared__ __attribute__((aligned(16))) bf16 As[3][128 * 32];
  __shared__ __attribute__((aligned(16))) bf16 Bs[3][128 * 32];

  const int bf = *dflag;
  const bf16* Bw = bf ? ((const bf16*)Braw + boff) : Barena;

  const int tid  = threadIdx.x;
  const int lane = tid & 63;
  const int q    = lane >> 4;     // quad 0..3
  const int m16  = lane & 15;
  const int w    = tid >> 6;      // wave 0..3
  const int wr   = w >> 1, wc = w & 1;   // 2x2 wave grid, 64x64 per wave

  int bx = blockIdx.x, by = blockIdx.y;
  if (SWZ) {
    int gx = gridDim.x, gy = gridDim.y;
    int n  = gx * gy;
    if ((n & 7) == 0) {
      int id  = by * gx + bx;
      int nid = (id & 7) * (n >> 3) + (id >> 3);   // bijective XCD chunk
      bx = nid / gy;                                // y-fastest: B-tile reuse
      by = nid % gy;
    }
  }

  const int rowA0 = by * 128;   // M-tile base
  const int rowB0 = bx * 128;   // N-tile base

  f32x4 acc[4][4] = {};

  const int NT = K >> 5;        // K-steps of 32

  // stage K-step kt into LDS slot: 512 16B chunks / tile.
  // chunk ci -> LDS bytes [ci*16, ci*16+16): row = ci>>2, k-chunk = ci&3.
  // LDS base is wave-uniform (tid & 192 == wave*64); HW scatters lane*16.
  auto stage = [&](int slot, int kt) {
    int k0 = kt << 5;
#pragma unroll
    for (int r = 0; r < 2; r++) {
      int ci  = r * 256 + tid;
      int row = ci >> 2;
      int kc  = ci & 3;
      const bf16* ga = A  + (size_t)(rowA0 + row) * K + (k0 + kc * 8);
      const bf16* gb = Bw + (size_t)(rowB0 + row) * K + (k0 + kc * 8);
      char* la = (char*)&As[slot][0] + (size_t)(r * 256 + (tid & 192)) * 16;
      char* lb = (char*)&Bs[slot][0] + (size_t)(r * 256 + (tid & 192)) * 16;
      async16(ga, la);
      async16(gb, lb);
    }
  };

  stage(0, 0);
  stage(1, 1 < NT ? 1 : 0);

  for (int t = 0; t < NT; t++) {
    int t2 = t + 2; if (t2 >= NT) t2 -= NT;        // wrap (redundant, harmless)
    stage((t + 2) % 3, t2);

    asm volatile("s_waitcnt vmcnt(8)" ::: "memory");   // S(t) done, S(t+1..2) in flight
    __builtin_amdgcn_s_barrier();

    const int sl = t % 3;
    bf16x8 af[4], bfr[4];
#pragma unroll
    for (int mt = 0; mt < 4; mt++)
      af[mt] = *(const bf16x8*)&As[sl][(wr * 64 + mt * 16 + m16) * 32 + q * 8];
#pragma unroll
    for (int nt = 0; nt < 4; nt++)
      bfr[nt] = *(const bf16x8*)&Bs[sl][(wc * 64 + nt * 16 + m16) * 32 + q * 8];

    asm volatile("s_waitcnt lgkmcnt(0)" ::: "memory"); // reads done before restage
    __builtin_amdgcn_sched_barrier(0);
    __builtin_amdgcn_s_barrier();

#pragma unroll
    for (int mt = 0; mt < 4; mt++)
#pragma unroll
      for (int nt = 0; nt < 4; nt++)
        acc[mt][nt] = __builtin_amdgcn_mfma_f32_16x16x32_bf16(
            af[mt], bfr[nt], acc[mt][nt], 0, 0, 0);
  }

  // drain wrapped prefetches before LDS is handed to the next workgroup
  asm volatile("s_waitcnt vmcnt(0)" ::: "memory");

  // epilogue: C/D layout col = lane&15, row = quad*4 + reg  [m89/m91]
#pragma unroll
  for (int mt = 0; mt < 4; mt++) {
#pragma unroll
    for (int r = 0; r < 4; r++) {
      int row = rowA0 + wr * 64 + mt * 16 + q * 4 + r;
#pragma unroll
      for (int nt = 0; nt < 4; nt++) {
        int col = rowB0 + wc * 64 + nt * 16 + m16;
        float v = acc[mt][nt][r];
        if (bias) v += rdf(bias, biasoff + col, bf);
        if (res)  v += res[(size_t)row * N + col];
        if (RELU) v = fmaxf(v, 0.f);
        size_t oi = (size_t)row * N + col;
        if (OUTMODE == 1 || (OUTMODE == 2 && bf)) ((bf16*)Cout)[oi] = f2b(v);
        else                                      ((float*)Cout)[oi] = v;
      }
    }
  }
}

// ---------------------------------------------------------------------------
// x[bt,:] = tok_emb[idx[bt],:] + pos_emb[t,:]   (dual-dtype reads, f32 out)
// ---------------------------------------------------------------------------
__global__ void embed_k(const int* __restrict__ idx, const void* __restrict__ tok,
                        const void* __restrict__ pos, float* __restrict__ x,
                        const int* __restrict__ dflag)
{
  int bf = *dflag;
  int bt = blockIdx.x;
  int t  = bt & (SEQ_T - 1);
  long rowv = idx[bt];
  for (int i = threadIdx.x; i < D_MODEL; i += blockDim.x)
    x[(size_t)bt * D_MODEL + i] = rdf(tok, rowv * D_MODEL + i, bf)
                                + rdf(pos, (long)t * D_MODEL + i, bf);
}

// ---------------------------------------------------------------------------
// LayerNorm over D_MODEL=512, one wave per row. f32 in, bf16 out.
// ---------------------------------------------------------------------------
__global__ __launch_bounds__(64) void ln_k(const float* __restrict__ x,
                                           const void* __restrict__ g,
                                           const void* __restrict__ bb,
                                           long goff,
                                           bf16* __restrict__ out,
                                           const int* __restrict__ dflag)
{
  int bf = *dflag;
  int row = blockIdx.x;
  const float4* xr = (const float4*)(x + (size_t)row * D_MODEL);
  int l = threadIdx.x;
  float4 v0 = xr[l];
  float4 v1 = xr[64 + l];
  float s  = (v0.x + v0.y) + (v0.z + v0.w) + (v1.x + v1.y) + (v1.z + v1.w);
  float ss = v0.x*v0.x + v0.y*v0.y + v0.z*v0.z + v0.w*v0.w
           + v1.x*v1.x + v1.y*v1.y + v1.z*v1.z + v1.w*v1.w;
#pragma unroll
  for (int o = 32; o; o >>= 1) { s += __shfl_xor(s, o); ss += __shfl_xor(ss, o); }
  float m   = s  * (1.f / 512.f);
  float var = ss * (1.f / 512.f) - m * m;
  float inv = rsqrtf(var + 1e-5f);
  float vs[8] = {v0.x, v0.y, v0.z, v0.w, v1.x, v1.y, v1.z, v1.w};
  int i0 = l * 4, i1 = 256 + l * 4;
#pragma unroll
  for (int e = 0; e < 4; e++) {
    out[(size_t)row * D_MODEL + i0 + e] =
        f2b((vs[e] - m) * inv * rdf(g, goff + i0 + e, bf) + rdf(bb, goff + i0 + e, bf));
    out[(size_t)row * D_MODEL + i1 + e] =
        f2b((vs[4 + e] - m) * inv * rdf(g, goff + i1 + e, bf) + rdf(bb, goff + i1 + e, bf));
  }
}

// ---------------------------------------------------------------------------
// causal depthwise conv (DC=4) over u-half of xz (f32), + bias, SiLU -> bf16 u
// ---------------------------------------------------------------------------
__global__ __launch_bounds__(256) void conv_silu_k(const float* __restrict__ xz,
                                                   const void* __restrict__ cw,
                                                   const void* __restrict__ cb,
                                                   long cwoff, long cboff,
                                                   bf16* __restrict__ u,
                                                   const int* __restrict__ dflag)
{
  int bf  = *dflag;
  int gid = blockIdx.x * 256 + threadIdx.x;
  int d   = gid & (D_INNER - 1);
  int bt  = gid >> 10;
  int t   = bt & (SEQ_T - 1);
  float acc = rdf(cb, cboff + d, bf);
#pragma unroll
  for (int k = 0; k < D_CONV; k++) {
    int tt = t + k - (D_CONV - 1);
    if (tt >= 0)
      acc += xz[(size_t)(bt + k - (D_CONV - 1)) * (2 * D_INNER) + d]
           * rdf(cw, cwoff + (long)d * D_CONV + k, bf);
  }
  float sig = 1.f / (1.f + __expf(-acc));
  u[gid] = f2b(acc * sig);
}

// ---------------------------------------------------------------------------
// x_dbl[t,0:64] = u[t,:] @ W_xp^T  (K=1024, N=64). One block per token.
// ---------------------------------------------------------------------------
__global__ __launch_bounds__(256) void xdbl_k(const bf16* __restrict__ u,
                                              const bf16* __restrict__ Warena,
                                              const void* __restrict__ Wraw, long woff,
                                              float* __restrict__ xd,
                                              const int* __restrict__ dflag)
{
  int bf = *dflag;
  const bf16* Wxp = bf ? ((const bf16*)Wraw + woff) : Warena;
  int t = blockIdx.x;
  __shared__ float us[D_INNER];
  __shared__ float red[256];
  if (threadIdx.x < D_INNER / 8) {
    bf16x8 v = *(const bf16x8*)(u + (size_t)t * D_INNER + threadIdx.x * 8);
#pragma unroll
    for (int e = 0; e < 8; e++) us[threadIdx.x * 8 + e] = b2f(v[e]);
  }
  __syncthreads();
  int j = threadIdx.x >> 2, p = threadIdx.x & 3;
  const bf16x8* wr = (const bf16x8*)(Wxp + (size_t)j * D_INNER + p * 256);
  float s = 0.f;
#pragma unroll 4
  for (int c = 0; c < 32; c++) {
    bf16x8 wv = wr[c];
    int k = p * 256 + c * 8;
#pragma unroll
    for (int e = 0; e < 8; e++) s += us[k + e] * b2f(wv[e]);
  }
  red[threadIdx.x] = s;
  __syncthreads();
  if (p == 0)
    xd[(size_t)t * 64 + j] = red[threadIdx.x] + red[threadIdx.x + 1]
                           + red[threadIdx.x + 2] + red[threadIdx.x + 3];
}

// ---------------------------------------------------------------------------
// dt[t,d] = softplus(x_dbl[t,0:32] @ W_dt[d,:]^T + b_dt[d])   (K=32)
// ---------------------------------------------------------------------------
__global__ __launch_bounds__(256) void dt_k(const float* __restrict__ xd,
                                            const bf16* __restrict__ Warena,
                                            const void* __restrict__ Wraw, long woff,
                                            const void* __restrict__ bdt, long boff,
                                            float* __restrict__ dtb,
                                            const int* __restrict__ dflag)
{
  int bf = *dflag;
  const bf16* Wdt = bf ? ((const bf16*)Wraw + woff) : Warena;
  int t = blockIdx.x >> 2;
  int d = ((blockIdx.x & 3) << 8) + threadIdx.x;
  __shared__ float xr[DT_RANK];
  if (threadIdx.x < DT_RANK) xr[threadIdx.x] = xd[(size_t)t * 64 + threadIdx.x];
  __syncthreads();
  float s = rdf(bdt, boff + d, bf);
  const bf16x8* wr = (const bf16x8*)(Wdt + (size_t)d * DT_RANK);
#pragma unroll
  for (int c = 0; c < 4; c++) {
    bf16x8 wv = wr[c];
#pragma unroll
    for (int e = 0; e < 8; e++) s += xr[c * 8 + e] * b2f(wv[e]);
  }
  s = (s > 20.f) ? s : log1pf(__expf(s));
  dtb[(size_t)t * D_INNER + d] = s;
}

// ---------------------------------------------------------------------------
// Chunked selective scan (see Round-0 notes): A computes per-chunk (P,Q),
// B does the tiny sequential composite fix-up, C replays chunks from Hin.
// ---------------------------------------------------------------------------
__global__ __launch_bounds__(256) void scanA_k(const float* __restrict__ dtb,
                                               const bf16* __restrict__ u,
                                               const float* __restrict__ xd,
                                               const void* __restrict__ A_log, long aoff,
                                               float* __restrict__ Pb,
                                               float* __restrict__ Qb,
                                               const int* __restrict__ dflag)
{
  int bf = *dflag;
  int s  = threadIdx.x & 15;
  int dl = threadIdx.x >> 4;          // 0..15
  int c  = blockIdx.x & (NCHUNK - 1);
  int dg = (blockIdx.x >> 4) & 63;
  int b  = blockIdx.x >> 10;
  int d  = dg * 16 + dl;

  float Av = -__expf(rdf(A_log, aoff + (long)d * D_STATE + s, bf));
  float h = 0.f, P = 1.f;
  size_t row0 = (size_t)b * SEQ_T + (size_t)c * CHUNK;

  float dt_n = dtb[row0 * D_INNER + d];
  float u_n  = b2f(u[row0 * D_INNER + d]);
  float B_n  = xd[row0 * 64 + DT_RANK + s];

  for (int t = 0; t < CHUNK; t++) {
    float dt_v = dt_n, u_v = u_n, Bv = B_n;
    if (t + 1 < CHUNK) {
      size_t r1 = row0 + t + 1;
      dt_n = dtb[r1 * D_INNER + d];
      u_n  = b2f(u[r1 * D_INNER + d]);
      B_n  = xd[r1 * 64 + DT_RANK + s];
    }
    float dA = __expf(dt_v * Av);
    P *= dA;
    h = dA * h + (dt_v * u_v) * Bv;
  }
  size_t o = (((size_t)b * D_INNER + d) * D_STATE + s) * NCHUNK + c;
  Pb[o] = P;
  Qb[o] = h;
}

__global__ __launch_bounds__(256) void scanB_k(const float* __restrict__ Pb,
                                               const float* __restrict__ Qb,
                                               float* __restrict__ Hin)
{
  int tid = blockIdx.x * 256 + threadIdx.x;   // one per (b,d,s)
  size_t base = (size_t)tid * NCHUNK;
  float h = 0.f;
#pragma unroll
  for (int c = 0; c < NCHUNK; c++) {
    Hin[base + c] = h;
    h = Pb[base + c] * h + Qb[base + c];
  }
}

__global__ __launch_bounds__(256) void scanC_k(const float* __restrict__ dtb,
                                               const bf16* __restrict__ u,
                                               const float* __restrict__ xd,
                                               const float* __restrict__ xz,
                                               const void* __restrict__ A_log, long aoff,
                                               const void* __restrict__ D_p, long doff,
                                               const float* __restrict__ Hin,
                                               bf16* __restrict__ y,
                                               const int* __restrict__ dflag)
{
  int bf = *dflag;
  int s  = threadIdx.x & 15;
  int dl = threadIdx.x >> 4;
  int c  = blockIdx.x & (NCHUNK - 1);
  int dg = (blockIdx.x >> 4) & 63;
  int b  = blockIdx.x >> 10;
  int d  = dg * 16 + dl;

  float Av = -__expf(rdf(A_log, aoff + (long)d * D_STATE + s, bf));
  float Dv = rdf(D_p, doff + d, bf);
  float h  = Hin[(((size_t)b * D_INNER + d) * D_STATE + s) * NCHUNK + c];
  size_t row0 = (size_t)b * SEQ_T + (size_t)c * CHUNK;

  float dt_n = dtb[row0 * D_INNER + d];
  float u_n  = b2f(u[row0 * D_INNER + d]);
  float B_n  = xd[row0 * 64 + DT_RANK + s];
  float C_n  = xd[row0 * 64 + DT_RANK + D_STATE + s];

  for (int t = 0; t < CHUNK; t++) {
    float dt_v = dt_n, u_v = u_n, Bv = B_n, Cv = C_n;
    if (t + 1 < CHUNK) {
      size_t r1 = row0 + t + 1;
      dt_n = dtb[r1 * D_INNER + d];
      u_n  = b2f(u[r1 * D_INNER + d]);
      B_n  = xd[r1 * 64 + DT_RANK + s];
      C_n  = xd[r1 * 64 + DT_RANK + D_STATE + s];
    }
    float dA = __expf(dt_v * Av);
    h = dA * h + (dt_v * u_v) * Bv;
    float p = h * Cv;
    p += __shfl_xor(p, 1);
    p += __shfl_xor(p, 2);
    p += __shfl_xor(p, 4);
    p += __shfl_xor(p, 8);
    if (s == 0) {
      size_t r = row0 + t;
      float zv  = xz[r * (2 * D_INNER) + D_INNER + d];
      float sig = 1.f / (1.f + __expf(-zv));
      y[r * D_INNER + d] = f2b((p + u_v * Dv) * (zv * sig));
    }
  }
}

// ---------------------------------------------------------------------------
__global__ void cast_k(const float* __restrict__ x, bf16* __restrict__ o, int n)
{
  int i = blockIdx.x * 256 + threadIdx.x;
  if (i < n) o[i] = f2b(x[i]);
}

// ---------------------------------------------------------------------------
extern "C" void kernel_launch(void* const* d_in, const int* in_sizes, int n_in,
                              void* d_out, int out_size, void* d_ws, size_t ws_size,
                              hipStream_t stream)
{
  const int* idx = (const int*)d_in[0];
  const void* tok    = d_in[1];
  const void* pos    = d_in[2];
  const void* ln1_g  = d_in[3];
  const void* ln1_b  = d_in[4];
  const void* W_in   = d_in[5];
  const void* conv_w = d_in[6];
  const void* conv_b = d_in[7];
  const void* W_xp   = d_in[8];
  const void* W_dt   = d_in[9];
  const void* b_dt   = d_in[10];
  const void* A_log  = d_in[11];
  const void* D_p    = d_in[12];
  const void* W_out  = d_in[13];
  const void* ln2_g  = d_in[14];
  const void* ln2_b  = d_in[15];
  const void* W_f1   = d_in[16];
  const void* b_f1   = d_in[17];
  const void* W_f2   = d_in[18];
  const void* b_f2   = d_in[19];
  const void* lm_w   = d_in[20];
  const void* lm_b   = d_in[21];

  char* ws = (char*)d_ws;
  int*  dflag = (int*)ws;    ws += 256;
  float* x_res = (float*)ws; ws += (size_t)BT * D_MODEL * 4;
  float* xz    = (float*)ws; ws += (size_t)BT * 2 * D_INNER * 4;
  float* xdbl  = (float*)ws; ws += (size_t)BT * 64 * 4;
  float* dtb   = (float*)ws; ws += (size_t)BT * D_INNER * 4;
  bf16* lnbuf  = (bf16*)ws;  ws += (size_t)BT * D_MODEL * 2;
  bf16* ubuf   = (bf16*)ws;  ws += (size_t)BT * D_INNER * 2;
  bf16* ybuf   = (bf16*)ws;  ws += (size_t)BT * D_INNER * 2;
  bf16* hbuf   = (bf16*)ws;  ws += (size_t)BT * H_FFN * 2;
  // chunked-scan composites: [B, D_INNER, D_STATE, NCHUNK] f32 each
  float* Pbuf  = (float*)ws; ws += (size_t)BATCH * D_INNER * D_STATE * NCHUNK * 4;
  float* Qbuf  = (float*)ws; ws += (size_t)BATCH * D_INNER * D_STATE * NCHUNK * 4;
  float* Hin   = (float*)ws; ws += (size_t)BATCH * D_INNER * D_STATE * NCHUNK * 4;
  // bf16 canonical weight arena (filled only when inputs are f32)
  bf16* aW_in  = (bf16*)ws;  ws += (size_t)N_LAYER * 2*D_INNER * D_MODEL * 2;
  bf16* aW_xp  = (bf16*)ws;  ws += (size_t)N_LAYER * 64 * D_INNER * 2;
  bf16* aW_dt  = (bf16*)ws;  ws += (size_t)N_LAYER * D_INNER * DT_RANK * 2;
  bf16* aW_out = (bf16*)ws;  ws += (size_t)N_LAYER * D_MODEL * D_INNER * 2;
  bf16* aW_f1  = (bf16*)ws;  ws += (size_t)N_LAYER * H_FFN * D_MODEL * 2;
  bf16* aW_f2  = (bf16*)ws;  ws += (size_t)N_LAYER * D_MODEL * H_FFN * 2;
  bf16* aLm    = (bf16*)ws;  ws += (size_t)VOCAB * D_MODEL * 2;

  probe_k<<<1, 64, 0, stream>>>((const unsigned short*)tok,
                                (const unsigned short*)pos, dflag);

  auto cvt = [&](const void* src, bf16* dst, long n) {
    int n4 = (int)(n / 4);
    cvt_k<<<(n4 + 255) / 256, 256, 0, stream>>>((const float4*)src, dst, n4, dflag);
  };
  cvt(W_in,  aW_in,  (long)N_LAYER * 2*D_INNER * D_MODEL);
  cvt(W_xp,  aW_xp,  (long)N_LAYER * 64 * D_INNER);
  cvt(W_dt,  aW_dt,  (long)N_LAYER * D_INNER * DT_RANK);
  cvt(W_out, aW_out, (long)N_LAYER * D_MODEL * D_INNER);
  cvt(W_f1,  aW_f1,  (long)N_LAYER * H_FFN * D_MODEL);
  cvt(W_f2,  aW_f2,  (long)N_LAYER * D_MODEL * H_FFN);
  cvt(lm_w,  aLm,    (long)VOCAB * D_MODEL);

  embed_k<<<BT, 256, 0, stream>>>(idx, tok, pos, x_res, dflag);

  for (int l = 0; l < N_LAYER; l++) {
    long oWin = (long)l * 2*D_INNER * D_MODEL;
    long oWxp = (long)l * 64 * D_INNER;
    long oWdt = (long)l * D_INNER * DT_RANK;
    long oWo  = (long)l * D_MODEL * D_INNER;
    long oWf1 = (long)l * H_FFN * D_MODEL;
    long oWf2 = (long)l * D_MODEL * H_FFN;
    long oA   = (long)l * D_INNER * D_STATE;
    long oD   = (long)l * D_INNER;

    ln_k<<<BT, 64, 0, stream>>>(x_res, ln1_g, ln1_b, (long)l * D_MODEL, lnbuf, dflag);

    gemm_nt<0, false, false><<<dim3(2 * D_INNER / 128, BT / 128), 256, 0, stream>>>(
        lnbuf, aW_in + oWin, W_in, oWin, xz, nullptr, 0, nullptr, dflag,
        BT, 2 * D_INNER, D_MODEL);

    conv_silu_k<<<BT * D_INNER / 256, 256, 0, stream>>>(
        xz, conv_w, conv_b, (long)l * D_INNER * D_CONV, oD, ubuf, dflag);

    xdbl_k<<<BT, 256, 0, stream>>>(ubuf, aW_xp + oWxp, W_xp, oWxp, xdbl, dflag);

    dt_k<<<BT * 4, 256, 0, stream>>>(
        xdbl, aW_dt + oWdt, W_dt, oWdt, b_dt, oD, dtb, dflag);

    scanA_k<<<BATCH * 64 * NCHUNK, 256, 0, stream>>>(
        dtb, ubuf, xdbl, A_log, oA, Pbuf, Qbuf, dflag);
    scanB_k<<<BATCH * D_INNER * D_STATE / 256, 256, 0, stream>>>(Pbuf, Qbuf, Hin);
    scanC_k<<<BATCH * 64 * NCHUNK, 256, 0, stream>>>(
        dtb, ubuf, xdbl, xz, A_log, oA, D_p, oD, Hin, ybuf, dflag);

    gemm_nt<0, false, false><<<dim3(D_MODEL / 128, BT / 128), 256, 0, stream>>>(
        ybuf, aW_out + oWo, W_out, oWo, x_res, nullptr, 0, x_res, dflag,
        BT, D_MODEL, D_INNER);

    ln_k<<<BT, 64, 0, stream>>>(x_res, ln2_g, ln2_b, (long)l * D_MODEL, lnbuf, dflag);

    gemm_nt<1, true, false><<<dim3(H_FFN / 128, BT / 128), 256, 0, stream>>>(
        lnbuf, aW_f1 + oWf1, W_f1, oWf1, hbuf, b_f1, (long)l * H_FFN, nullptr, dflag,
        BT, H_FFN, D_MODEL);

    gemm_nt<0, false, false><<<dim3(D_MODEL / 128, BT / 128), 256, 0, stream>>>(
        hbuf, aW_f2 + oWf2, W_f2, oWf2, x_res, b_f2, (long)l * D_MODEL, x_res, dflag,
        BT, D_MODEL, H_FFN);
  }

  cast_k<<<BT * D_MODEL / 256, 256, 0, stream>>>(x_res, lnbuf, BT * D_MODEL);

  gemm_nt<2, false, true><<<dim3(VOCAB / 128, BT / 128), 256, 0, stream>>>(
      lnbuf, aLm, lm_w, 0, d_out, lm_b, 0, nullptr, dflag,
      BT, VOCAB, D_MODEL);
}

// Round 3
// 1500.693 us; speedup vs baseline: 1.2259x; 1.2259x over previous
//
#include <hip/hip_runtime.h>
#include <cstdint>
#include <cstddef>

typedef __bf16 bf16;
typedef __bf16 bf16x8 __attribute__((ext_vector_type(8)));
typedef __bf16 bf16x4 __attribute__((ext_vector_type(4)));
typedef float  f32x4  __attribute__((ext_vector_type(4)));

#define D_MODEL 512
#define D_INNER 1024
#define D_STATE 16
#define D_CONV  4
#define DT_RANK 32
#define N_LAYER 4
#define H_FFN   2048
#define SEQ_T   1024
#define BATCH   2
#define BT      (BATCH * SEQ_T)   // 2048 tokens
#define VOCAB   32000

// chunked scan parameters
#define NCHUNK  16
#define CHUNK   (SEQ_T / NCHUNK)  // 64

// split-K for small-N GEMMs
#define KSPLIT  4

__device__ __forceinline__ float b2f(bf16 x) { return (float)x; }
__device__ __forceinline__ bf16  f2b(float x) { return (bf16)x; }

// dual-dtype scalar read: p holds bf16 if bf!=0 else f32
__device__ __forceinline__ float rdf(const void* p, long i, int bf) {
  return bf ? (float)((const bf16*)p)[i] : ((const float*)p)[i];
}

__device__ __forceinline__ void async16(const void* g, void* l) {
  __builtin_amdgcn_global_load_lds((const __attribute__((address_space(1))) void*)g,
                                   (__attribute__((address_space(3))) void*)l, 16, 0, 0);
}

// ---------------------------------------------------------------------------
// dtype probe: flag=1 -> inputs are bf16 (see earlier rounds).
// ---------------------------------------------------------------------------
__global__ void probe_k(const unsigned short* __restrict__ tok,
                        const unsigned short* __restrict__ pos,
                        int* __restrict__ flag)
{
  int lane = threadIdx.x;
  int bad = 0;
  for (int i = lane; i < 512; i += 64) {
    int e0 = (tok[i] >> 7) & 0xFF;
    int e1 = (pos[i] >> 7) & 0xFF;
    if (e0 >= 134 || e1 >= 134) bad = 1;   // |v|>=128 or inf/nan
  }
  unsigned long long m = __ballot(bad);
  if (lane == 0) *flag = (m == 0ULL) ? 1 : 0;
}

// f32 -> bf16 arena conversion (no-op when inputs are already bf16)
__global__ __launch_bounds__(256) void cvt_k(const float4* __restrict__ src,
                                             bf16* __restrict__ dst,
                                             int n4, const int* __restrict__ dflag)
{
  if (*dflag) return;
  int i = blockIdx.x * 256 + threadIdx.x;
  if (i >= n4) return;
  float4 v = src[i];
  bf16x4 o; o[0] = f2b(v.x); o[1] = f2b(v.y); o[2] = f2b(v.z); o[3] = f2b(v.w);
  *(bf16x4*)(dst + (size_t)i * 4) = o;
}

// ---------------------------------------------------------------------------
// NT GEMM: C[M,N'] = A[M,K] * B[N',K]^T. 128x128 tile, BK=32, 4 waves,
// mfma_f32_16x16x32_bf16, global_load_lds width-16 staging, single-buffer
// sync loop (round-1 form: measured best; counted-vmcnt pipeline regressed
// in this 128^2/4-wave structure -> reverted).
// ldc = C row stride; col0 = column base (for N-split launches).
// SWZ: bijective XCD-chunk remap, y-fastest (B-tile reuse per XCD).
// OUTMODE: 0=f32, 1=bf16, 2=select by flag (final logits).
// ---------------------------------------------------------------------------
template<int OUTMODE, bool RELU, bool SWZ>
__global__ __launch_bounds__(256) void gemm_nt(
    const bf16* __restrict__ A, const bf16* __restrict__ Barena,
    const void* __restrict__ Braw, long boff,
    void* __restrict__ Cout, const void* __restrict__ bias, long biasoff,
    const float* __restrict__ res, const int* __restrict__ dflag,
    int M, int N, int K, int ldc, int col0)
{
  __shared__ __attribute__((aligned(16))) bf16 As[128 * 32];
  __shared__ __attribute__((aligned(16))) bf16 Bs[128 * 32];

  const int bf = *dflag;
  const bf16* Bw = bf ? ((const bf16*)Braw + boff) : Barena;

  const int tid  = threadIdx.x;
  const int lane = tid & 63;
  const int q    = lane >> 4;     // quad 0..3
  const int m16  = lane & 15;
  const int w    = tid >> 6;      // wave 0..3
  const int wr   = w >> 1, wc = w & 1;   // 2x2 wave grid, 64x64 per wave

  int bx = blockIdx.x, by = blockIdx.y;
  if (SWZ) {
    int gx = gridDim.x, gy = gridDim.y;
    int n  = gx * gy;
    if ((n & 7) == 0) {
      int id  = by * gx + bx;
      int nid = (id & 7) * (n >> 3) + (id >> 3);   // bijective XCD chunk
      bx = nid / gy;                                // y-fastest: B-tile reuse
      by = nid % gy;
    }
  }

  const int rowA0 = by * 128;   // M-tile base
  const int rowB0 = bx * 128;   // N-tile base

  f32x4 acc[4][4] = {};

  for (int k0 = 0; k0 < K; k0 += 32) {
    // stage A-tile and B-tile (128x32 bf16 each) as 512 16B chunks / tile.
    // chunk ci -> LDS bytes [ci*16, ci*16+16): row = ci>>2, k-chunk = ci&3.
    // LDS base is wave-uniform (tid & 192 == wave*64); HW scatters lane*16.
#pragma unroll
    for (int r = 0; r < 2; r++) {
      int ci  = r * 256 + tid;
      int row = ci >> 2;
      int kc  = ci & 3;
      const bf16* ga = A  + (size_t)(rowA0 + row) * K + (k0 + kc * 8);
      const bf16* gb = Bw + (size_t)(rowB0 + row) * K + (k0 + kc * 8);
      char* la = (char*)As + (size_t)(r * 256 + (tid & 192)) * 16;
      char* lb = (char*)Bs + (size_t)(r * 256 + (tid & 192)) * 16;
      async16(ga, la);
      async16(gb, lb);
    }
    __syncthreads();

    bf16x8 af[4], bfr[4];
#pragma unroll
    for (int mt = 0; mt < 4; mt++)
      af[mt] = *(const bf16x8*)&As[(wr * 64 + mt * 16 + m16) * 32 + q * 8];
#pragma unroll
    for (int nt = 0; nt < 4; nt++)
      bfr[nt] = *(const bf16x8*)&Bs[(wc * 64 + nt * 16 + m16) * 32 + q * 8];

#pragma unroll
    for (int mt = 0; mt < 4; mt++)
#pragma unroll
      for (int nt = 0; nt < 4; nt++)
        acc[mt][nt] = __builtin_amdgcn_mfma_f32_16x16x32_bf16(
            af[mt], bfr[nt], acc[mt][nt], 0, 0, 0);

    __syncthreads();
  }

  // epilogue: C/D layout col = lane&15, row = quad*4 + reg  [m89/m91]
#pragma unroll
  for (int mt = 0; mt < 4; mt++) {
#pragma unroll
    for (int r = 0; r < 4; r++) {
      int row = rowA0 + wr * 64 + mt * 16 + q * 4 + r;
#pragma unroll
      for (int nt = 0; nt < 4; nt++) {
        int col = col0 + rowB0 + wc * 64 + nt * 16 + m16;
        float v = acc[mt][nt][r];
        if (bias) v += rdf(bias, biasoff + col, bf);
        if (res)  v += res[(size_t)row * ldc + col];
        if (RELU) v = fmaxf(v, 0.f);
        size_t oi = (size_t)row * ldc + col;
        if (OUTMODE == 1 || (OUTMODE == 2 && bf)) ((bf16*)Cout)[oi] = f2b(v);
        else                                      ((float*)Cout)[oi] = v;
      }
    }
  }
}

// ---------------------------------------------------------------------------
// Split-K NT GEMM: partial C_ks[M,N] = A[M, ks-slice] * B[N, ks-slice]^T.
// Same tile/loop structure; blockIdx.z selects the K slice. f32 partials.
// Fixes the grid=64-blocks regime of the N=512 GEMMs (3/4 of CUs idle).
// ---------------------------------------------------------------------------
__global__ __launch_bounds__(256) void gemm_nt_sk(
    const bf16* __restrict__ A, const bf16* __restrict__ Barena,
    const void* __restrict__ Braw, long boff,
    float* __restrict__ Cpart, const int* __restrict__ dflag,
    int M, int N, int K)
{
  __shared__ __attribute__((aligned(16))) bf16 As[128 * 32];
  __shared__ __attribute__((aligned(16))) bf16 Bs[128 * 32];

  const int bf = *dflag;
  const bf16* Bw = bf ? ((const bf16*)Braw + boff) : Barena;

  const int tid  = threadIdx.x;
  const int lane = tid & 63;
  const int q    = lane >> 4;
  const int m16  = lane & 15;
  const int w    = tid >> 6;
  const int wr   = w >> 1, wc = w & 1;

  const int rowA0 = blockIdx.y * 128;
  const int rowB0 = blockIdx.x * 128;
  const int ks    = blockIdx.z;
  const int kBeg  = ks * (K / KSPLIT);
  const int kEnd  = kBeg + (K / KSPLIT);

  f32x4 acc[4][4] = {};

  for (int k0 = kBeg; k0 < kEnd; k0 += 32) {
#pragma unroll
    for (int r = 0; r < 2; r++) {
      int ci  = r * 256 + tid;
      int row = ci >> 2;
      int kc  = ci & 3;
      const bf16* ga = A  + (size_t)(rowA0 + row) * K + (k0 + kc * 8);
      const bf16* gb = Bw + (size_t)(rowB0 + row) * K + (k0 + kc * 8);
      char* la = (char*)As + (size_t)(r * 256 + (tid & 192)) * 16;
      char* lb = (char*)Bs + (size_t)(r * 256 + (tid & 192)) * 16;
      async16(ga, la);
      async16(gb, lb);
    }
    __syncthreads();

    bf16x8 af[4], bfr[4];
#pragma unroll
    for (int mt = 0; mt < 4; mt++)
      af[mt] = *(const bf16x8*)&As[(wr * 64 + mt * 16 + m16) * 32 + q * 8];
#pragma unroll
    for (int nt = 0; nt < 4; nt++)
      bfr[nt] = *(const bf16x8*)&Bs[(wc * 64 + nt * 16 + m16) * 32 + q * 8];

#pragma unroll
    for (int mt = 0; mt < 4; mt++)
#pragma unroll
      for (int nt = 0; nt < 4; nt++)
        acc[mt][nt] = __builtin_amdgcn_mfma_f32_16x16x32_bf16(
            af[mt], bfr[nt], acc[mt][nt], 0, 0, 0);

    __syncthreads();
  }

#pragma unroll
  for (int mt = 0; mt < 4; mt++) {
#pragma unroll
    for (int r = 0; r < 4; r++) {
      int row = rowA0 + wr * 64 + mt * 16 + q * 4 + r;
#pragma unroll
      for (int nt = 0; nt < 4; nt++) {
        int col = rowB0 + wc * 64 + nt * 16 + m16;
        Cpart[((size_t)ks * M + row) * N + col] = acc[mt][nt][r];
      }
    }
  }
}

// reduce KSPLIT partials + optional bias + optional residual -> f32 out.
// n = M*N/4 float4 elements; N must be a power of two.
__global__ __launch_bounds__(256) void redk_k(const float* __restrict__ part,
                                              const void* __restrict__ bias, long biasoff,
                                              const float* __restrict__ res,
                                              float* __restrict__ out,
                                              int n, int N, const int* __restrict__ dflag)
{
  int bf = *dflag;
  int i = blockIdx.x * 256 + threadIdx.x;
  if (i >= n) return;
  f32x4 s = ((const f32x4*)part)[i];
#pragma unroll
  for (int ks = 1; ks < KSPLIT; ks++) {
    f32x4 p = ((const f32x4*)part)[(size_t)ks * n + i];
    s.x += p.x; s.y += p.y; s.z += p.z; s.w += p.w;
  }
  if (bias) {
    int col = (i * 4) & (N - 1);
    s.x += rdf(bias, biasoff + col,     bf);
    s.y += rdf(bias, biasoff + col + 1, bf);
    s.z += rdf(bias, biasoff + col + 2, bf);
    s.w += rdf(bias, biasoff + col + 3, bf);
  }
  if (res) {
    f32x4 r = ((const f32x4*)res)[i];
    s.x += r.x; s.y += r.y; s.z += r.z; s.w += r.w;
  }
  ((f32x4*)out)[i] = s;
}

// ---------------------------------------------------------------------------
// x[bt,:] = tok_emb[idx[bt],:] + pos_emb[t,:]   (dual-dtype reads, f32 out)
// ---------------------------------------------------------------------------
__global__ void embed_k(const int* __restrict__ idx, const void* __restrict__ tok,
                        const void* __restrict__ pos, float* __restrict__ x,
                        const int* __restrict__ dflag)
{
  int bf = *dflag;
  int bt = blockIdx.x;
  int t  = bt & (SEQ_T - 1);
  long rowv = idx[bt];
  for (int i = threadIdx.x; i < D_MODEL; i += blockDim.x)
    x[(size_t)bt * D_MODEL + i] = rdf(tok, rowv * D_MODEL + i, bf)
                                + rdf(pos, (long)t * D_MODEL + i, bf);
}

// ---------------------------------------------------------------------------
// LayerNorm over D_MODEL=512, one wave per row. f32 in, bf16 out.
// ---------------------------------------------------------------------------
__global__ __launch_bounds__(64) void ln_k(const float* __restrict__ x,
                                           const void* __restrict__ g,
                                           const void* __restrict__ bb,
                                           long goff,
                                           bf16* __restrict__ out,
                                           const int* __restrict__ dflag)
{
  int bf = *dflag;
  int row = blockIdx.x;
  const float4* xr = (const float4*)(x + (size_t)row * D_MODEL);
  int l = threadIdx.x;
  float4 v0 = xr[l];
  float4 v1 = xr[64 + l];
  float s  = (v0.x + v0.y) + (v0.z + v0.w) + (v1.x + v1.y) + (v1.z + v1.w);
  float ss = v0.x*v0.x + v0.y*v0.y + v0.z*v0.z + v0.w*v0.w
           + v1.x*v1.x + v1.y*v1.y + v1.z*v1.z + v1.w*v1.w;
#pragma unroll
  for (int o = 32; o; o >>= 1) { s += __shfl_xor(s, o); ss += __shfl_xor(ss, o); }
  float m   = s  * (1.f / 512.f);
  float var = ss * (1.f / 512.f) - m * m;
  float inv = rsqrtf(var + 1e-5f);
  float vs[8] = {v0.x, v0.y, v0.z, v0.w, v1.x, v1.y, v1.z, v1.w};
  int i0 = l * 4, i1 = 256 + l * 4;
#pragma unroll
  for (int e = 0; e < 4; e++) {
    out[(size_t)row * D_MODEL + i0 + e] =
        f2b((vs[e] - m) * inv * rdf(g, goff + i0 + e, bf) + rdf(bb, goff + i0 + e, bf));
    out[(size_t)row * D_MODEL + i1 + e] =
        f2b((vs[4 + e] - m) * inv * rdf(g, goff + i1 + e, bf) + rdf(bb, goff + i1 + e, bf));
  }
}

// ---------------------------------------------------------------------------
// causal depthwise conv (DC=4) over u-half of xz (f32), + bias, SiLU -> bf16 u
// ---------------------------------------------------------------------------
__global__ __launch_bounds__(256) void conv_silu_k(const float* __restrict__ xz,
                                                   const void* __restrict__ cw,
                                                   const void* __restrict__ cb,
                                                   long cwoff, long cboff,
                                                   bf16* __restrict__ u,
                                                   const int* __restrict__ dflag)
{
  int bf  = *dflag;
  int gid = blockIdx.x * 256 + threadIdx.x;
  int d   = gid & (D_INNER - 1);
  int bt  = gid >> 10;
  int t   = bt & (SEQ_T - 1);
  float acc = rdf(cb, cboff + d, bf);
#pragma unroll
  for (int k = 0; k < D_CONV; k++) {
    int tt = t + k - (D_CONV - 1);
    if (tt >= 0)
      acc += xz[(size_t)(bt + k - (D_CONV - 1)) * (2 * D_INNER) + d]
           * rdf(cw, cwoff + (long)d * D_CONV + k, bf);
  }
  float sig = 1.f / (1.f + __expf(-acc));
  u[gid] = f2b(acc * sig);
}

// ---------------------------------------------------------------------------
// x_dbl[t,0:64] = u[t,:] @ W_xp^T  (K=1024, N=64). One block per token.
// ---------------------------------------------------------------------------
__global__ __launch_bounds__(256) void xdbl_k(const bf16* __restrict__ u,
                                              const bf16* __restrict__ Warena,
                                              const void* __restrict__ Wraw, long woff,
                                              float* __restrict__ xd,
                                              const int* __restrict__ dflag)
{
  int bf = *dflag;
  const bf16* Wxp = bf ? ((const bf16*)Wraw + woff) : Warena;
  int t = blockIdx.x;
  __shared__ float us[D_INNER];
  __shared__ float red[256];
  if (threadIdx.x < D_INNER / 8) {
    bf16x8 v = *(const bf16x8*)(u + (size_t)t * D_INNER + threadIdx.x * 8);
#pragma unroll
    for (int e = 0; e < 8; e++) us[threadIdx.x * 8 + e] = b2f(v[e]);
  }
  __syncthreads();
  int j = threadIdx.x >> 2, p = threadIdx.x & 3;
  const bf16x8* wr = (const bf16x8*)(Wxp + (size_t)j * D_INNER + p * 256);
  float s = 0.f;
#pragma unroll 4
  for (int c = 0; c < 32; c++) {
    bf16x8 wv = wr[c];
    int k = p * 256 + c * 8;
#pragma unroll
    for (int e = 0; e < 8; e++) s += us[k + e] * b2f(wv[e]);
  }
  red[threadIdx.x] = s;
  __syncthreads();
  if (p == 0)
    xd[(size_t)t * 64 + j] = red[threadIdx.x] + red[threadIdx.x + 1]
                           + red[threadIdx.x + 2] + red[threadIdx.x + 3];
}

// ---------------------------------------------------------------------------
// dt[t,d] = softplus(x_dbl[t,0:32] @ W_dt[d,:]^T + b_dt[d])   (K=32)
// ---------------------------------------------------------------------------
__global__ __launch_bounds__(256) void dt_k(const float* __restrict__ xd,
                                            const bf16* __restrict__ Warena,
                                            const void* __restrict__ Wraw, long woff,
                                            const void* __restrict__ bdt, long boff,
                                            float* __restrict__ dtb,
                                            const int* __restrict__ dflag)
{
  int bf = *dflag;
  const bf16* Wdt = bf ? ((const bf16*)Wraw + woff) : Warena;
  int t = blockIdx.x >> 2;
  int d = ((blockIdx.x & 3) << 8) + threadIdx.x;
  __shared__ float xr[DT_RANK];
  if (threadIdx.x < DT_RANK) xr[threadIdx.x] = xd[(size_t)t * 64 + threadIdx.x];
  __syncthreads();
  float s = rdf(bdt, boff + d, bf);
  const bf16x8* wr = (const bf16x8*)(Wdt + (size_t)d * DT_RANK);
#pragma unroll
  for (int c = 0; c < 4; c++) {
    bf16x8 wv = wr[c];
#pragma unroll
    for (int e = 0; e < 8; e++) s += xr[c * 8 + e] * b2f(wv[e]);
  }
  s = (s > 20.f) ? s : log1pf(__expf(s));
  dtb[(size_t)t * D_INNER + d] = s;
}

// ---------------------------------------------------------------------------
// Chunked selective scan (see Round-0 notes): A computes per-chunk (P,Q),
// B does the tiny sequential composite fix-up, C replays chunks from Hin.
// ---------------------------------------------------------------------------
__global__ __launch_bounds__(256) void scanA_k(const float* __restrict__ dtb,
                                               const bf16* __restrict__ u,
                                               const float* __restrict__ xd,
                                               const void* __restrict__ A_log, long aoff,
                                               float* __restrict__ Pb,
                                               float* __restrict__ Qb,
                                               const int* __restrict__ dflag)
{
  int bf = *dflag;
  int s  = threadIdx.x & 15;
  int dl = threadIdx.x >> 4;          // 0..15
  int c  = blockIdx.x & (NCHUNK - 1);
  int dg = (blockIdx.x >> 4) & 63;
  int b  = blockIdx.x >> 10;
  int d  = dg * 16 + dl;

  float Av = -__expf(rdf(A_log, aoff + (long)d * D_STATE + s, bf));
  float h = 0.f, P = 1.f;
  size_t row0 = (size_t)b * SEQ_T + (size_t)c * CHUNK;

  float dt_n = dtb[row0 * D_INNER + d];
  float u_n  = b2f(u[row0 * D_INNER + d]);
  float B_n  = xd[row0 * 64 + DT_RANK + s];

  for (int t = 0; t < CHUNK; t++) {
    float dt_v = dt_n, u_v = u_n, Bv = B_n;
    if (t + 1 < CHUNK) {
      size_t r1 = row0 + t + 1;
      dt_n = dtb[r1 * D_INNER + d];
      u_n  = b2f(u[r1 * D_INNER + d]);
      B_n  = xd[r1 * 64 + DT_RANK + s];
    }
    float dA = __expf(dt_v * Av);
    P *= dA;
    h = dA * h + (dt_v * u_v) * Bv;
  }
  size_t o = (((size_t)b * D_INNER + d) * D_STATE + s) * NCHUNK + c;
  Pb[o] = P;
  Qb[o] = h;
}

__global__ __launch_bounds__(256) void scanB_k(const float* __restrict__ Pb,
                                               const float* __restrict__ Qb,
                                               float* __restrict__ Hin)
{
  int tid = blockIdx.x * 256 + threadIdx.x;   // one per (b,d,s)
  size_t base = (size_t)tid * NCHUNK;
  float h = 0.f;
#pragma unroll
  for (int c = 0; c < NCHUNK; c++) {
    Hin[base + c] = h;
    h = Pb[base + c] * h + Qb[base + c];
  }
}

__global__ __launch_bounds__(256) void scanC_k(const float* __restrict__ dtb,
                                               const bf16* __restrict__ u,
                                               const float* __restrict__ xd,
                                               const float* __restrict__ xz,
                                               const void* __restrict__ A_log, long aoff,
                                               const void* __restrict__ D_p, long doff,
                                               const float* __restrict__ Hin,
                                               bf16* __restrict__ y,
                                               const int* __restrict__ dflag)
{
  int bf = *dflag;
  int s  = threadIdx.x & 15;
  int dl = threadIdx.x >> 4;
  int c  = blockIdx.x & (NCHUNK - 1);
  int dg = (blockIdx.x >> 4) & 63;
  int b  = blockIdx.x >> 10;
  int d  = dg * 16 + dl;

  float Av = -__expf(rdf(A_log, aoff + (long)d * D_STATE + s, bf));
  float Dv = rdf(D_p, doff + d, bf);
  float h  = Hin[(((size_t)b * D_INNER + d) * D_STATE + s) * NCHUNK + c];
  size_t row0 = (size_t)b * SEQ_T + (size_t)c * CHUNK;

  float dt_n = dtb[row0 * D_INNER + d];
  float u_n  = b2f(u[row0 * D_INNER + d]);
  float B_n  = xd[row0 * 64 + DT_RANK + s];
  float C_n  = xd[row0 * 64 + DT_RANK + D_STATE + s];

  for (int t = 0; t < CHUNK; t++) {
    float dt_v = dt_n, u_v = u_n, Bv = B_n, Cv = C_n;
    if (t + 1 < CHUNK) {
      size_t r1 = row0 + t + 1;
      dt_n = dtb[r1 * D_INNER + d];
      u_n  = b2f(u[r1 * D_INNER + d]);
      B_n  = xd[r1 * 64 + DT_RANK + s];
      C_n  = xd[r1 * 64 + DT_RANK + D_STATE + s];
    }
    float dA = __expf(dt_v * Av);
    h = dA * h + (dt_v * u_v) * Bv;
    float p = h * Cv;
    p += __shfl_xor(p, 1);
    p += __shfl_xor(p, 2);
    p += __shfl_xor(p, 4);
    p += __shfl_xor(p, 8);
    if (s == 0) {
      size_t r = row0 + t;
      float zv  = xz[r * (2 * D_INNER) + D_INNER + d];
      float sig = 1.f / (1.f + __expf(-zv));
      y[r * D_INNER + d] = f2b((p + u_v * Dv) * (zv * sig));
    }
  }
}

// ---------------------------------------------------------------------------
__global__ void cast_k(const float* __restrict__ x, bf16* __restrict__ o, int n)
{
  int i = blockIdx.x * 256 + threadIdx.x;
  if (i < n) o[i] = f2b(x[i]);
}

// ---------------------------------------------------------------------------
extern "C" void kernel_launch(void* const* d_in, const int* in_sizes, int n_in,
                              void* d_out, int out_size, void* d_ws, size_t ws_size,
                              hipStream_t stream)
{
  const int* idx = (const int*)d_in[0];
  const void* tok    = d_in[1];
  const void* pos    = d_in[2];
  const void* ln1_g  = d_in[3];
  const void* ln1_b  = d_in[4];
  const void* W_in   = d_in[5];
  const void* conv_w = d_in[6];
  const void* conv_b = d_in[7];
  const void* W_xp   = d_in[8];
  const void* W_dt   = d_in[9];
  const void* b_dt   = d_in[10];
  const void* A_log  = d_in[11];
  const void* D_p    = d_in[12];
  const void* W_out  = d_in[13];
  const void* ln2_g  = d_in[14];
  const void* ln2_b  = d_in[15];
  const void* W_f1   = d_in[16];
  const void* b_f1   = d_in[17];
  const void* W_f2   = d_in[18];
  const void* b_f2   = d_in[19];
  const void* lm_w   = d_in[20];
  const void* lm_b   = d_in[21];

  char* ws = (char*)d_ws;
  int*  dflag = (int*)ws;    ws += 256;
  float* x_res = (float*)ws; ws += (size_t)BT * D_MODEL * 4;
  float* xz    = (float*)ws; ws += (size_t)BT * 2 * D_INNER * 4;
  float* xdbl  = (float*)ws; ws += (size_t)BT * 64 * 4;
  float* dtb   = (float*)ws; ws += (size_t)BT * D_INNER * 4;
  bf16* lnbuf  = (bf16*)ws;  ws += (size_t)BT * D_MODEL * 2;
  bf16* ubuf   = (bf16*)ws;  ws += (size_t)BT * D_INNER * 2;
  bf16* ybuf   = (bf16*)ws;  ws += (size_t)BT * D_INNER * 2;
  bf16* hbuf   = (bf16*)ws;  ws += (size_t)BT * H_FFN * 2;
  // split-K partials: [KSPLIT, BT, D_MODEL] f32
  float* cpart = (float*)ws; ws += (size_t)KSPLIT * BT * D_MODEL * 4;
  // chunked-scan composites: [B, D_INNER, D_STATE, NCHUNK] f32 each
  float* Pbuf  = (float*)ws; ws += (size_t)BATCH * D_INNER * D_STATE * NCHUNK * 4;
  float* Qbuf  = (float*)ws; ws += (size_t)BATCH * D_INNER * D_STATE * NCHUNK * 4;
  float* Hin   = (float*)ws; ws += (size_t)BATCH * D_INNER * D_STATE * NCHUNK * 4;
  // bf16 canonical weight arena (filled only when inputs are f32)
  bf16* aW_in  = (bf16*)ws;  ws += (size_t)N_LAYER * 2*D_INNER * D_MODEL * 2;
  bf16* aW_xp  = (bf16*)ws;  ws += (size_t)N_LAYER * 64 * D_INNER * 2;
  bf16* aW_dt  = (bf16*)ws;  ws += (size_t)N_LAYER * D_INNER * DT_RANK * 2;
  bf16* aW_out = (bf16*)ws;  ws += (size_t)N_LAYER * D_MODEL * D_INNER * 2;
  bf16* aW_f1  = (bf16*)ws;  ws += (size_t)N_LAYER * H_FFN * D_MODEL * 2;
  bf16* aW_f2  = (bf16*)ws;  ws += (size_t)N_LAYER * D_MODEL * H_FFN * 2;
  bf16* aLm    = (bf16*)ws;  ws += (size_t)VOCAB * D_MODEL * 2;

  probe_k<<<1, 64, 0, stream>>>((const unsigned short*)tok,
                                (const unsigned short*)pos, dflag);

  auto cvt = [&](const void* src, bf16* dst, long n) {
    int n4 = (int)(n / 4);
    cvt_k<<<(n4 + 255) / 256, 256, 0, stream>>>((const float4*)src, dst, n4, dflag);
  };
  cvt(W_in,  aW_in,  (long)N_LAYER * 2*D_INNER * D_MODEL);
  cvt(W_xp,  aW_xp,  (long)N_LAYER * 64 * D_INNER);
  cvt(W_dt,  aW_dt,  (long)N_LAYER * D_INNER * DT_RANK);
  cvt(W_out, aW_out, (long)N_LAYER * D_MODEL * D_INNER);
  cvt(W_f1,  aW_f1,  (long)N_LAYER * H_FFN * D_MODEL);
  cvt(W_f2,  aW_f2,  (long)N_LAYER * D_MODEL * H_FFN);
  cvt(lm_w,  aLm,    (long)VOCAB * D_MODEL);

  embed_k<<<BT, 256, 0, stream>>>(idx, tok, pos, x_res, dflag);

  for (int l = 0; l < N_LAYER; l++) {
    long oWin = (long)l * 2*D_INNER * D_MODEL;
    long oWxp = (long)l * 64 * D_INNER;
    long oWdt = (long)l * D_INNER * DT_RANK;
    long oWo  = (long)l * D_MODEL * D_INNER;
    long oWf1 = (long)l * H_FFN * D_MODEL;
    long oWf2 = (long)l * D_MODEL * H_FFN;
    long oA   = (long)l * D_INNER * D_STATE;
    long oD   = (long)l * D_INNER;

    ln_k<<<BT, 64, 0, stream>>>(x_res, ln1_g, ln1_b, (long)l * D_MODEL, lnbuf, dflag);

    gemm_nt<0, false, false><<<dim3(2 * D_INNER / 128, BT / 128), 256, 0, stream>>>(
        lnbuf, aW_in + oWin, W_in, oWin, xz, nullptr, 0, nullptr, dflag,
        BT, 2 * D_INNER, D_MODEL, 2 * D_INNER, 0);

    conv_silu_k<<<BT * D_INNER / 256, 256, 0, stream>>>(
        xz, conv_w, conv_b, (long)l * D_INNER * D_CONV, oD, ubuf, dflag);

    xdbl_k<<<BT, 256, 0, stream>>>(ubuf, aW_xp + oWxp, W_xp, oWxp, xdbl, dflag);

    dt_k<<<BT * 4, 256, 0, stream>>>(
        xdbl, aW_dt + oWdt, W_dt, oWdt, b_dt, oD, dtb, dflag);

    scanA_k<<<BATCH * 64 * NCHUNK, 256, 0, stream>>>(
        dtb, ubuf, xdbl, A_log, oA, Pbuf, Qbuf, dflag);
    scanB_k<<<BATCH * D_INNER * D_STATE / 256, 256, 0, stream>>>(Pbuf, Qbuf, Hin);
    scanC_k<<<BATCH * 64 * NCHUNK, 256, 0, stream>>>(
        dtb, ubuf, xdbl, xz, A_log, oA, D_p, oD, Hin, ybuf, dflag);

    // W_out: M=2048 N=512 K=1024 -> split-K x4 (grid 64 -> 256 blocks)
    gemm_nt_sk<<<dim3(D_MODEL / 128, BT / 128, KSPLIT), 256, 0, stream>>>(
        ybuf, aW_out + oWo, W_out, oWo, cpart, dflag, BT, D_MODEL, D_INNER);
    redk_k<<<(BT * D_MODEL / 4 + 255) / 256, 256, 0, stream>>>(
        cpart, nullptr, 0, x_res, x_res, BT * D_MODEL / 4, D_MODEL, dflag);

    ln_k<<<BT, 64, 0, stream>>>(x_res, ln2_g, ln2_b, (long)l * D_MODEL, lnbuf, dflag);

    gemm_nt<1, true, false><<<dim3(H_FFN / 128, BT / 128), 256, 0, stream>>>(
        lnbuf, aW_f1 + oWf1, W_f1, oWf1, hbuf, b_f1, (long)l * H_FFN, nullptr, dflag,
        BT, H_FFN, D_MODEL, H_FFN, 0);

    // FFN2: M=2048 N=512 K=2048 -> split-K x4
    gemm_nt_sk<<<dim3(D_MODEL / 128, BT / 128, KSPLIT), 256, 0, stream>>>(
        hbuf, aW_f2 + oWf2, W_f2, oWf2, cpart, dflag, BT, D_MODEL, H_FFN);
    redk_k<<<(BT * D_MODEL / 4 + 255) / 256, 256, 0, stream>>>(
        cpart, b_f2, (long)l * D_MODEL, x_res, x_res, BT * D_MODEL / 4, D_MODEL, dflag);
  }

  cast_k<<<BT * D_MODEL / 256, 256, 0, stream>>>(x_res, lnbuf, BT * D_MODEL);

  // logits in two N-halves (~95 us each): same total work, and lets any
  // hidden dispatch >= ~95 us surface in the rocprof top-5.
  for (int h = 0; h < 2; h++) {
    int colbase = h * (VOCAB / 2);
    gemm_nt<2, false, true><<<dim3(VOCAB / 2 / 128, BT / 128), 256, 0, stream>>>(
        lnbuf, aLm + (size_t)colbase * D_MODEL, lm_w, (long)colbase * D_MODEL,
        d_out, lm_b, 0, nullptr, dflag,
        BT, VOCAB / 2, D_MODEL, VOCAB, colbase);
  }
}

// Round 5
// 1446.286 us; speedup vs baseline: 1.2720x; 1.0376x over previous
//
#include <hip/hip_runtime.h>
#include <cstdint>
#include <cstddef>

typedef __bf16 bf16;
typedef __bf16 bf16x8 __attribute__((ext_vector_type(8)));
typedef __bf16 bf16x4 __attribute__((ext_vector_type(4)));
typedef float  f32x4  __attribute__((ext_vector_type(4)));

#define D_MODEL 512
#define D_INNER 1024
#define D_STATE 16
#define D_CONV  4
#define DT_RANK 32
#define N_LAYER 4
#define H_FFN   2048
#define SEQ_T   1024
#define BATCH   2
#define BT      (BATCH * SEQ_T)   // 2048 tokens
#define VOCAB   32000

// chunked scan parameters
#define NCHUNK  16
#define CHUNK   (SEQ_T / NCHUNK)  // 64

// split-K for small-N GEMMs
#define KSPLIT  4

__device__ __forceinline__ float b2f(bf16 x) { return (float)x; }
__device__ __forceinline__ bf16  f2b(float x) { return (bf16)x; }

// dual-dtype scalar read: p holds bf16 if bf!=0 else f32
__device__ __forceinline__ float rdf(const void* p, long i, int bf) {
  return bf ? (float)((const bf16*)p)[i] : ((const float*)p)[i];
}

__device__ __forceinline__ void async16(const void* g, void* l) {
  __builtin_amdgcn_global_load_lds((const __attribute__((address_space(1))) void*)g,
                                   (__attribute__((address_space(3))) void*)l, 16, 0, 0);
}

// ---------------------------------------------------------------------------
// dtype probe: flag=1 -> inputs are bf16 (see earlier rounds).
// ---------------------------------------------------------------------------
__global__ void probe_k(const unsigned short* __restrict__ tok,
                        const unsigned short* __restrict__ pos,
                        int* __restrict__ flag)
{
  int lane = threadIdx.x;
  int bad = 0;
  for (int i = lane; i < 512; i += 64) {
    int e0 = (tok[i] >> 7) & 0xFF;
    int e1 = (pos[i] >> 7) & 0xFF;
    if (e0 >= 134 || e1 >= 134) bad = 1;   // |v|>=128 or inf/nan
  }
  unsigned long long m = __ballot(bad);
  if (lane == 0) *flag = (m == 0ULL) ? 1 : 0;
}

// f32 -> bf16 arena conversion (no-op when inputs are already bf16)
__global__ __launch_bounds__(256) void cvt_k(const float4* __restrict__ src,
                                             bf16* __restrict__ dst,
                                             int n4, const int* __restrict__ dflag)
{
  if (*dflag) return;
  int i = blockIdx.x * 256 + threadIdx.x;
  if (i >= n4) return;
  float4 v = src[i];
  bf16x4 o; o[0] = f2b(v.x); o[1] = f2b(v.y); o[2] = f2b(v.z); o[3] = f2b(v.w);
  *(bf16x4*)(dst + (size_t)i * 4) = o;
}

// ---------------------------------------------------------------------------
// NT GEMM: C[M,N'] = A[M,K] * B[N',K]^T.  BM=128 x BN tile (BN = 128 or 64),
// BK=32, 4 waves in 2x2 grid (per-wave 64 x BN/2), mfma_f32_16x16x32_bf16,
// global_load_lds width-16 staging, single-buffer sync loop (measured best
// for this structure; counted-vmcnt pipeline regressed -> keep 2-phase).
// BN=64 exists for mid-size GEMMs whose 128^2 grid was 1 block/CU (1
// wave/SIMD): the 2-phase drain had zero sibling waves to hide under.
// 512 blocks -> 2 blocks/CU -> implicit inter-block overlap (m114).
// ldc = C row stride; col0 = column base (for N-split launches).
// SWZ: bijective XCD-chunk remap, y-fastest (B-tile reuse per XCD).
// OUTMODE: 0=f32, 1=bf16, 2=select by flag (final logits).
// ---------------------------------------------------------------------------
template<int OUTMODE, bool RELU, bool SWZ, int BN>
__global__ __launch_bounds__(256) void gemm_nt(
    const bf16* __restrict__ A, const bf16* __restrict__ Barena,
    const void* __restrict__ Braw, long boff,
    void* __restrict__ Cout, const void* __restrict__ bias, long biasoff,
    const float* __restrict__ res, const int* __restrict__ dflag,
    int M, int N, int K, int ldc, int col0)
{
  constexpr int WN  = BN / 2;     // wave column extent
  constexpr int NTF = WN / 16;    // n-frags per wave (4 or 2)
  constexpr int BCH = BN / 64;    // B staging chunk-iters (2 or 1)

  __shared__ __attribute__((aligned(16))) bf16 As[128 * 32];
  __shared__ __attribute__((aligned(16))) bf16 Bs[BN * 32];

  const int bf = *dflag;
  const bf16* Bw = bf ? ((const bf16*)Braw + boff) : Barena;

  const int tid  = threadIdx.x;
  const int lane = tid & 63;
  const int q    = lane >> 4;     // quad 0..3
  const int m16  = lane & 15;
  const int w    = tid >> 6;      // wave 0..3
  const int wr   = w >> 1, wc = w & 1;   // 2x2 wave grid

  int bx = blockIdx.x, by = blockIdx.y;
  if (SWZ) {
    int gx = gridDim.x, gy = gridDim.y;
    int n  = gx * gy;
    if ((n & 7) == 0) {
      int id  = by * gx + bx;
      int nid = (id & 7) * (n >> 3) + (id >> 3);   // bijective XCD chunk
      bx = nid / gy;                                // y-fastest: B-tile reuse
      by = nid % gy;
    }
  }

  const int rowA0 = by * 128;   // M-tile base
  const int rowB0 = bx * BN;    // N-tile base

  f32x4 acc[4][NTF] = {};

  for (int k0 = 0; k0 < K; k0 += 32) {
    // stage tiles as 16B chunks; chunk ci -> row = ci>>2, k-chunk = ci&3.
    // LDS base is wave-uniform (tid & 192 == wave*64); HW scatters lane*16.
#pragma unroll
    for (int r = 0; r < 2; r++) {
      int ci  = r * 256 + tid;
      const bf16* ga = A + (size_t)(rowA0 + (ci >> 2)) * K + (k0 + (ci & 3) * 8);
      char* la = (char*)As + (size_t)(r * 256 + (tid & 192)) * 16;
      async16(ga, la);
    }
#pragma unroll
    for (int r = 0; r < BCH; r++) {
      int ci  = r * 256 + tid;
      const bf16* gb = Bw + (size_t)(rowB0 + (ci >> 2)) * K + (k0 + (ci & 3) * 8);
      char* lb = (char*)Bs + (size_t)(r * 256 + (tid & 192)) * 16;
      async16(gb, lb);
    }
    __syncthreads();

    bf16x8 af[4], bfr[NTF];
#pragma unroll
    for (int mt = 0; mt < 4; mt++)
      af[mt] = *(const bf16x8*)&As[(wr * 64 + mt * 16 + m16) * 32 + q * 8];
#pragma unroll
    for (int nt = 0; nt < NTF; nt++)
      bfr[nt] = *(const bf16x8*)&Bs[(wc * WN + nt * 16 + m16) * 32 + q * 8];

#pragma unroll
    for (int mt = 0; mt < 4; mt++)
#pragma unroll
      for (int nt = 0; nt < NTF; nt++)
        acc[mt][nt] = __builtin_amdgcn_mfma_f32_16x16x32_bf16(
            af[mt], bfr[nt], acc[mt][nt], 0, 0, 0);

    __syncthreads();
  }

  // epilogue: C/D layout col = lane&15, row = quad*4 + reg  [m89/m91]
#pragma unroll
  for (int mt = 0; mt < 4; mt++) {
#pragma unroll
    for (int r = 0; r < 4; r++) {
      int row = rowA0 + wr * 64 + mt * 16 + q * 4 + r;
#pragma unroll
      for (int nt = 0; nt < NTF; nt++) {
        int col = col0 + rowB0 + wc * WN + nt * 16 + m16;
        float v = acc[mt][nt][r];
        if (bias) v += rdf(bias, biasoff + col, bf);
        if (res)  v += res[(size_t)row * ldc + col];
        if (RELU) v = fmaxf(v, 0.f);
        size_t oi = (size_t)row * ldc + col;
        if (OUTMODE == 1 || (OUTMODE == 2 && bf)) ((bf16*)Cout)[oi] = f2b(v);
        else                                      ((float*)Cout)[oi] = v;
      }
    }
  }
}

// ---------------------------------------------------------------------------
// Split-K NT GEMM: partial C_ks[M,N] = A[M, ks-slice] * B[N, ks-slice]^T.
// 128x64 tile (same mapping as gemm_nt<...,64>); blockIdx.z = K slice.
// ---------------------------------------------------------------------------
__global__ __launch_bounds__(256) void gemm_nt_sk(
    const bf16* __restrict__ A, const bf16* __restrict__ Barena,
    const void* __restrict__ Braw, long boff,
    float* __restrict__ Cpart, const int* __restrict__ dflag,
    int M, int N, int K)
{
  __shared__ __attribute__((aligned(16))) bf16 As[128 * 32];
  __shared__ __attribute__((aligned(16))) bf16 Bs[64 * 32];

  const int bf = *dflag;
  const bf16* Bw = bf ? ((const bf16*)Braw + boff) : Barena;

  const int tid  = threadIdx.x;
  const int lane = tid & 63;
  const int q    = lane >> 4;
  const int m16  = lane & 15;
  const int w    = tid >> 6;
  const int wr   = w >> 1, wc = w & 1;

  const int rowA0 = blockIdx.y * 128;
  const int rowB0 = blockIdx.x * 64;
  const int ks    = blockIdx.z;
  const int kBeg  = ks * (K / KSPLIT);
  const int kEnd  = kBeg + (K / KSPLIT);

  f32x4 acc[4][2] = {};

  for (int k0 = kBeg; k0 < kEnd; k0 += 32) {
#pragma unroll
    for (int r = 0; r < 2; r++) {
      int ci  = r * 256 + tid;
      const bf16* ga = A + (size_t)(rowA0 + (ci >> 2)) * K + (k0 + (ci & 3) * 8);
      char* la = (char*)As + (size_t)(r * 256 + (tid & 192)) * 16;
      async16(ga, la);
    }
    {
      int ci  = tid;
      const bf16* gb = Bw + (size_t)(rowB0 + (ci >> 2)) * K + (k0 + (ci & 3) * 8);
      char* lb = (char*)Bs + (size_t)(tid & 192) * 16;
      async16(gb, lb);
    }
    __syncthreads();

    bf16x8 af[4], bfr[2];
#pragma unroll
    for (int mt = 0; mt < 4; mt++)
      af[mt] = *(const bf16x8*)&As[(wr * 64 + mt * 16 + m16) * 32 + q * 8];
#pragma unroll
    for (int nt = 0; nt < 2; nt++)
      bfr[nt] = *(const bf16x8*)&Bs[(wc * 32 + nt * 16 + m16) * 32 + q * 8];

#pragma unroll
    for (int mt = 0; mt < 4; mt++)
#pragma unroll
      for (int nt = 0; nt < 2; nt++)
        acc[mt][nt] = __builtin_amdgcn_mfma_f32_16x16x32_bf16(
            af[mt], bfr[nt], acc[mt][nt], 0, 0, 0);

    __syncthreads();
  }

#pragma unroll
  for (int mt = 0; mt < 4; mt++) {
#pragma unroll
    for (int r = 0; r < 4; r++) {
      int row = rowA0 + wr * 64 + mt * 16 + q * 4 + r;
#pragma unroll
      for (int nt = 0; nt < 2; nt++) {
        int col = rowB0 + wc * 32 + nt * 16 + m16;
        Cpart[((size_t)ks * M + row) * N + col] = acc[mt][nt][r];
      }
    }
  }
}

// ---------------------------------------------------------------------------
// Fused split-K reduce + epilogue. One wave per row (D_MODEL=512).
//   sum KSPLIT partials (+bias) (+res) -> x_res row (f32)
//   then DO_LN ? LayerNorm(g,b) : plain cast  -> bf16 out row
// Replaces redk_k + ln_k / cast_k and one 4 MB x_res round-trip.
// Add order matches the old redk_k (ks ascending, then bias, then res).
// ---------------------------------------------------------------------------
template<bool DO_LN>
__global__ __launch_bounds__(64) void redk_ln_k(
    const float* __restrict__ part,
    const void* __restrict__ bias, long biasoff,
    const float* __restrict__ res,
    float* __restrict__ xout,
    const void* __restrict__ g, const void* __restrict__ bb, long goff,
    bf16* __restrict__ out, const int* __restrict__ dflag)
{
  const int bf  = *dflag;
  const int row = blockIdx.x;
  const int l   = threadIdx.x;
  const size_t slice = (size_t)BT * (D_MODEL / 4);   // f32x4 units
  const f32x4* p = (const f32x4*)part + (size_t)row * (D_MODEL / 4);

  f32x4 a0 = p[l], a1 = p[64 + l];
#pragma unroll
  for (int ks = 1; ks < KSPLIT; ks++) {
    f32x4 q0 = p[ks * slice + l];
    f32x4 q1 = p[ks * slice + 64 + l];
    a0.x += q0.x; a0.y += q0.y; a0.z += q0.z; a0.w += q0.w;
    a1.x += q1.x; a1.y += q1.y; a1.z += q1.z; a1.w += q1.w;
  }
  int i0 = l * 4, i1 = 256 + l * 4;
  if (bias) {
    a0.x += rdf(bias, biasoff + i0,     bf);
    a0.y += rdf(bias, biasoff + i0 + 1, bf);
    a0.z += rdf(bias, biasoff + i0 + 2, bf);
    a0.w += rdf(bias, biasoff + i0 + 3, bf);
    a1.x += rdf(bias, biasoff + i1,     bf);
    a1.y += rdf(bias, biasoff + i1 + 1, bf);
    a1.z += rdf(bias, biasoff + i1 + 2, bf);
    a1.w += rdf(bias, biasoff + i1 + 3, bf);
  }
  if (res) {
    const f32x4* rr = (const f32x4*)(res + (size_t)row * D_MODEL);
    f32x4 r0 = rr[l], r1 = rr[64 + l];
    a0.x += r0.x; a0.y += r0.y; a0.z += r0.z; a0.w += r0.w;
    a1.x += r1.x; a1.y += r1.y; a1.z += r1.z; a1.w += r1.w;
  }
  f32x4* xo = (f32x4*)(xout + (size_t)row * D_MODEL);
  xo[l] = a0; xo[64 + l] = a1;

  float vs[8] = {a0.x, a0.y, a0.z, a0.w, a1.x, a1.y, a1.z, a1.w};
  if (DO_LN) {
    float s  = (a0.x + a0.y) + (a0.z + a0.w) + (a1.x + a1.y) + (a1.z + a1.w);
    float ss = a0.x*a0.x + a0.y*a0.y + a0.z*a0.z + a0.w*a0.w
             + a1.x*a1.x + a1.y*a1.y + a1.z*a1.z + a1.w*a1.w;
#pragma unroll
    for (int o = 32; o; o >>= 1) { s += __shfl_xor(s, o); ss += __shfl_xor(ss, o); }
    float m   = s  * (1.f / 512.f);
    float var = ss * (1.f / 512.f) - m * m;
    float inv = rsqrtf(var + 1e-5f);
#pragma unroll
    for (int e = 0; e < 4; e++) {
      out[(size_t)row * D_MODEL + i0 + e] =
          f2b((vs[e] - m) * inv * rdf(g, goff + i0 + e, bf) + rdf(bb, goff + i0 + e, bf));
      out[(size_t)row * D_MODEL + i1 + e] =
          f2b((vs[4 + e] - m) * inv * rdf(g, goff + i1 + e, bf) + rdf(bb, goff + i1 + e, bf));
    }
  } else {
#pragma unroll
    for (int e = 0; e < 4; e++) {
      out[(size_t)row * D_MODEL + i0 + e] = f2b(vs[e]);
      out[(size_t)row * D_MODEL + i1 + e] = f2b(vs[4 + e]);
    }
  }
}

// ---------------------------------------------------------------------------
// x[bt,:] = tok_emb[idx[bt],:] + pos_emb[t,:]   (dual-dtype reads, f32 out)
// ---------------------------------------------------------------------------
__global__ void embed_k(const int* __restrict__ idx, const void* __restrict__ tok,
                        const void* __restrict__ pos, float* __restrict__ x,
                        const int* __restrict__ dflag)
{
  int bf = *dflag;
  int bt = blockIdx.x;
  int t  = bt & (SEQ_T - 1);
  long rowv = idx[bt];
  for (int i = threadIdx.x; i < D_MODEL; i += blockDim.x)
    x[(size_t)bt * D_MODEL + i] = rdf(tok, rowv * D_MODEL + i, bf)
                                + rdf(pos, (long)t * D_MODEL + i, bf);
}

// ---------------------------------------------------------------------------
// LayerNorm over D_MODEL=512, one wave per row. f32 in, bf16 out.
// (only used once now: layer-0 ln1 after embed)
// ---------------------------------------------------------------------------
__global__ __launch_bounds__(64) void ln_k(const float* __restrict__ x,
                                           const void* __restrict__ g,
                                           const void* __restrict__ bb,
                                           long goff,
                                           bf16* __restrict__ out,
                                           const int* __restrict__ dflag)
{
  int bf = *dflag;
  int row = blockIdx.x;
  const float4* xr = (const float4*)(x + (size_t)row * D_MODEL);
  int l = threadIdx.x;
  float4 v0 = xr[l];
  float4 v1 = xr[64 + l];
  float s  = (v0.x + v0.y) + (v0.z + v0.w) + (v1.x + v1.y) + (v1.z + v1.w);
  float ss = v0.x*v0.x + v0.y*v0.y + v0.z*v0.z + v0.w*v0.w
           + v1.x*v1.x + v1.y*v1.y + v1.z*v1.z + v1.w*v1.w;
#pragma unroll
  for (int o = 32; o; o >>= 1) { s += __shfl_xor(s, o); ss += __shfl_xor(ss, o); }
  float m   = s  * (1.f / 512.f);
  float var = ss * (1.f / 512.f) - m * m;
  float inv = rsqrtf(var + 1e-5f);
  float vs[8] = {v0.x, v0.y, v0.z, v0.w, v1.x, v1.y, v1.z, v1.w};
  int i0 = l * 4, i1 = 256 + l * 4;
#pragma unroll
  for (int e = 0; e < 4; e++) {
    out[(size_t)row * D_MODEL + i0 + e] =
        f2b((vs[e] - m) * inv * rdf(g, goff + i0 + e, bf) + rdf(bb, goff + i0 + e, bf));
    out[(size_t)row * D_MODEL + i1 + e] =
        f2b((vs[4 + e] - m) * inv * rdf(g, goff + i1 + e, bf) + rdf(bb, goff + i1 + e, bf));
  }
}

// ---------------------------------------------------------------------------
// causal depthwise conv (DC=4) over u-half of xz (f32), + bias, SiLU -> bf16 u
// ---------------------------------------------------------------------------
__global__ __launch_bounds__(256) void conv_silu_k(const float* __restrict__ xz,
                                                   const void* __restrict__ cw,
                                                   const void* __restrict__ cb,
                                                   long cwoff, long cboff,
                                                   bf16* __restrict__ u,
                                                   const int* __restrict__ dflag)
{
  int bf  = *dflag;
  int gid = blockIdx.x * 256 + threadIdx.x;
  int d   = gid & (D_INNER - 1);
  int bt  = gid >> 10;
  int t   = bt & (SEQ_T - 1);
  float acc = rdf(cb, cboff + d, bf);
#pragma unroll
  for (int k = 0; k < D_CONV; k++) {
    int tt = t + k - (D_CONV - 1);
    if (tt >= 0)
      acc += xz[(size_t)(bt + k - (D_CONV - 1)) * (2 * D_INNER) + d]
           * rdf(cw, cwoff + (long)d * D_CONV + k, bf);
  }
  float sig = 1.f / (1.f + __expf(-acc));
  u[gid] = f2b(acc * sig);
}

// ---------------------------------------------------------------------------
// x_dbl[t,0:64] = u[t,:] @ W_xp^T  (K=1024, N=64). One block per token.
// ---------------------------------------------------------------------------
__global__ __launch_bounds__(256) void xdbl_k(const bf16* __restrict__ u,
                                              const bf16* __restrict__ Warena,
                                              const void* __restrict__ Wraw, long woff,
                                              float* __restrict__ xd,
                                              const int* __restrict__ dflag)
{
  int bf = *dflag;
  const bf16* Wxp = bf ? ((const bf16*)Wraw + woff) : Warena;
  int t = blockIdx.x;
  __shared__ float us[D_INNER];
  __shared__ float red[256];
  if (threadIdx.x < D_INNER / 8) {
    bf16x8 v = *(const bf16x8*)(u + (size_t)t * D_INNER + threadIdx.x * 8);
#pragma unroll
    for (int e = 0; e < 8; e++) us[threadIdx.x * 8 + e] = b2f(v[e]);
  }
  __syncthreads();
  int j = threadIdx.x >> 2, p = threadIdx.x & 3;
  const bf16x8* wr = (const bf16x8*)(Wxp + (size_t)j * D_INNER + p * 256);
  float s = 0.f;
#pragma unroll 4
  for (int c = 0; c < 32; c++) {
    bf16x8 wv = wr[c];
    int k = p * 256 + c * 8;
#pragma unroll
    for (int e = 0; e < 8; e++) s += us[k + e] * b2f(wv[e]);
  }
  red[threadIdx.x] = s;
  __syncthreads();
  if (p == 0)
    xd[(size_t)t * 64 + j] = red[threadIdx.x] + red[threadIdx.x + 1]
                           + red[threadIdx.x + 2] + red[threadIdx.x + 3];
}

// ---------------------------------------------------------------------------
// dt[t,d] = softplus(x_dbl[t,0:32] @ W_dt[d,:]^T + b_dt[d])   (K=32)
// ---------------------------------------------------------------------------
__global__ __launch_bounds__(256) void dt_k(const float* __restrict__ xd,
                                            const bf16* __restrict__ Warena,
                                            const void* __restrict__ Wraw, long woff,
                                            const void* __restrict__ bdt, long boff,
                                            float* __restrict__ dtb,
                                            const int* __restrict__ dflag)
{
  int bf = *dflag;
  const bf16* Wdt = bf ? ((const bf16*)Wraw + woff) : Warena;
  int t = blockIdx.x >> 2;
  int d = ((blockIdx.x & 3) << 8) + threadIdx.x;
  __shared__ float xr[DT_RANK];
  if (threadIdx.x < DT_RANK) xr[threadIdx.x] = xd[(size_t)t * 64 + threadIdx.x];
  __syncthreads();
  float s = rdf(bdt, boff + d, bf);
  const bf16x8* wr = (const bf16x8*)(Wdt + (size_t)d * DT_RANK);
#pragma unroll
  for (int c = 0; c < 4; c++) {
    bf16x8 wv = wr[c];
#pragma unroll
    for (int e = 0; e < 8; e++) s += xr[c * 8 + e] * b2f(wv[e]);
  }
  s = (s > 20.f) ? s : log1pf(__expf(s));
  dtb[(size_t)t * D_INNER + d] = s;
}

// ---------------------------------------------------------------------------
// Chunked selective scan (see Round-0 notes): A computes per-chunk (P,Q),
// B does the tiny sequential composite fix-up, C replays chunks from Hin.
// ---------------------------------------------------------------------------
__global__ __launch_bounds__(256) void scanA_k(const float* __restrict__ dtb,
                                               const bf16* __restrict__ u,
                                               const float* __restrict__ xd,
                                               const void* __restrict__ A_log, long aoff,
                                               float* __restrict__ Pb,
                                               float* __restrict__ Qb,
                                               const int* __restrict__ dflag)
{
  int bf = *dflag;
  int s  = threadIdx.x & 15;
  int dl = threadIdx.x >> 4;          // 0..15
  int c  = blockIdx.x & (NCHUNK - 1);
  int dg = (blockIdx.x >> 4) & 63;
  int b  = blockIdx.x >> 10;
  int d  = dg * 16 + dl;

  float Av = -__expf(rdf(A_log, aoff + (long)d * D_STATE + s, bf));
  float h = 0.f, P = 1.f;
  size_t row0 = (size_t)b * SEQ_T + (size_t)c * CHUNK;

  float dt_n = dtb[row0 * D_INNER + d];
  float u_n  = b2f(u[row0 * D_INNER + d]);
  float B_n  = xd[row0 * 64 + DT_RANK + s];

  for (int t = 0; t < CHUNK; t++) {
    float dt_v = dt_n, u_v = u_n, Bv = B_n;
    if (t + 1 < CHUNK) {
      size_t r1 = row0 + t + 1;
      dt_n = dtb[r1 * D_INNER + d];
      u_n  = b2f(u[r1 * D_INNER + d]);
      B_n  = xd[r1 * 64 + DT_RANK + s];
    }
    float dA = __expf(dt_v * Av);
    P *= dA;
    h = dA * h + (dt_v * u_v) * Bv;
  }
  size_t o = (((size_t)b * D_INNER + d) * D_STATE + s) * NCHUNK + c;
  Pb[o] = P;
  Qb[o] = h;
}

__global__ __launch_bounds__(256) void scanB_k(const float* __restrict__ Pb,
                                               const float* __restrict__ Qb,
                                               float* __restrict__ Hin)
{
  int tid = blockIdx.x * 256 + threadIdx.x;   // one per (b,d,s)
  size_t base = (size_t)tid * NCHUNK;
  float h = 0.f;
#pragma unroll
  for (int c = 0; c < NCHUNK; c++) {
    Hin[base + c] = h;
    h = Pb[base + c] * h + Qb[base + c];
  }
}

__global__ __launch_bounds__(256) void scanC_k(const float* __restrict__ dtb,
                                               const bf16* __restrict__ u,
                                               const float* __restrict__ xd,
                                               const float* __restrict__ xz,
                                               const void* __restrict__ A_log, long aoff,
                                               const void* __restrict__ D_p, long doff,
                                               const float* __restrict__ Hin,
                                               bf16* __restrict__ y,
                                               const int* __restrict__ dflag)
{
  int bf = *dflag;
  int s  = threadIdx.x & 15;
  int dl = threadIdx.x >> 4;
  int c  = blockIdx.x & (NCHUNK - 1);
  int dg = (blockIdx.x >> 4) & 63;
  int b  = blockIdx.x >> 10;
  int d  = dg * 16 + dl;

  float Av = -__expf(rdf(A_log, aoff + (long)d * D_STATE + s, bf));
  float Dv = rdf(D_p, doff + d, bf);
  float h  = Hin[(((size_t)b * D_INNER + d) * D_STATE + s) * NCHUNK + c];
  size_t row0 = (size_t)b * SEQ_T + (size_t)c * CHUNK;

  float dt_n = dtb[row0 * D_INNER + d];
  float u_n  = b2f(u[row0 * D_INNER + d]);
  float B_n  = xd[row0 * 64 + DT_RANK + s];
  float C_n  = xd[row0 * 64 + DT_RANK + D_STATE + s];

  for (int t = 0; t < CHUNK; t++) {
    float dt_v = dt_n, u_v = u_n, Bv = B_n, Cv = C_n;
    if (t + 1 < CHUNK) {
      size_t r1 = row0 + t + 1;
      dt_n = dtb[r1 * D_INNER + d];
      u_n  = b2f(u[r1 * D_INNER + d]);
      B_n  = xd[r1 * 64 + DT_RANK + s];
      C_n  = xd[r1 * 64 + DT_RANK + D_STATE + s];
    }
    float dA = __expf(dt_v * Av);
    h = dA * h + (dt_v * u_v) * Bv;
    float p = h * Cv;
    p += __shfl_xor(p, 1);
    p += __shfl_xor(p, 2);
    p += __shfl_xor(p, 4);
    p += __shfl_xor(p, 8);
    if (s == 0) {
      size_t r = row0 + t;
      float zv  = xz[r * (2 * D_INNER) + D_INNER + d];
      float sig = 1.f / (1.f + __expf(-zv));
      y[r * D_INNER + d] = f2b((p + u_v * Dv) * (zv * sig));
    }
  }
}

// ---------------------------------------------------------------------------
extern "C" void kernel_launch(void* const* d_in, const int* in_sizes, int n_in,
                              void* d_out, int out_size, void* d_ws, size_t ws_size,
                              hipStream_t stream)
{
  const int* idx = (const int*)d_in[0];
  const void* tok    = d_in[1];
  const void* pos    = d_in[2];
  const void* ln1_g  = d_in[3];
  const void* ln1_b  = d_in[4];
  const void* W_in   = d_in[5];
  const void* conv_w = d_in[6];
  const void* conv_b = d_in[7];
  const void* W_xp   = d_in[8];
  const void* W_dt   = d_in[9];
  const void* b_dt   = d_in[10];
  const void* A_log  = d_in[11];
  const void* D_p    = d_in[12];
  const void* W_out  = d_in[13];
  const void* ln2_g  = d_in[14];
  const void* ln2_b  = d_in[15];
  const void* W_f1   = d_in[16];
  const void* b_f1   = d_in[17];
  const void* W_f2   = d_in[18];
  const void* b_f2   = d_in[19];
  const void* lm_w   = d_in[20];
  const void* lm_b   = d_in[21];

  char* ws = (char*)d_ws;
  int*  dflag = (int*)ws;    ws += 256;
  float* x_res = (float*)ws; ws += (size_t)BT * D_MODEL * 4;
  float* xz    = (float*)ws; ws += (size_t)BT * 2 * D_INNER * 4;
  float* xdbl  = (float*)ws; ws += (size_t)BT * 64 * 4;
  float* dtb   = (float*)ws; ws += (size_t)BT * D_INNER * 4;
  bf16* lnbuf  = (bf16*)ws;  ws += (size_t)BT * D_MODEL * 2;
  bf16* ubuf   = (bf16*)ws;  ws += (size_t)BT * D_INNER * 2;
  bf16* ybuf   = (bf16*)ws;  ws += (size_t)BT * D_INNER * 2;
  bf16* hbuf   = (bf16*)ws;  ws += (size_t)BT * H_FFN * 2;
  // split-K partials: [KSPLIT, BT, D_MODEL] f32
  float* cpart = (float*)ws; ws += (size_t)KSPLIT * BT * D_MODEL * 4;
  // chunked-scan composites: [B, D_INNER, D_STATE, NCHUNK] f32 each
  float* Pbuf  = (float*)ws; ws += (size_t)BATCH * D_INNER * D_STATE * NCHUNK * 4;
  float* Qbuf  = (float*)ws; ws += (size_t)BATCH * D_INNER * D_STATE * NCHUNK * 4;
  float* Hin   = (float*)ws; ws += (size_t)BATCH * D_INNER * D_STATE * NCHUNK * 4;
  // bf16 canonical weight arena (filled only when inputs are f32)
  bf16* aW_in  = (bf16*)ws;  ws += (size_t)N_LAYER * 2*D_INNER * D_MODEL * 2;
  bf16* aW_xp  = (bf16*)ws;  ws += (size_t)N_LAYER * 64 * D_INNER * 2;
  bf16* aW_dt  = (bf16*)ws;  ws += (size_t)N_LAYER * D_INNER * DT_RANK * 2;
  bf16* aW_out = (bf16*)ws;  ws += (size_t)N_LAYER * D_MODEL * D_INNER * 2;
  bf16* aW_f1  = (bf16*)ws;  ws += (size_t)N_LAYER * H_FFN * D_MODEL * 2;
  bf16* aW_f2  = (bf16*)ws;  ws += (size_t)N_LAYER * D_MODEL * H_FFN * 2;
  bf16* aLm    = (bf16*)ws;  ws += (size_t)VOCAB * D_MODEL * 2;

  probe_k<<<1, 64, 0, stream>>>((const unsigned short*)tok,
                                (const unsigned short*)pos, dflag);

  auto cvt = [&](const void* src, bf16* dst, long n) {
    int n4 = (int)(n / 4);
    cvt_k<<<(n4 + 255) / 256, 256, 0, stream>>>((const float4*)src, dst, n4, dflag);
  };
  cvt(W_in,  aW_in,  (long)N_LAYER * 2*D_INNER * D_MODEL);
  cvt(W_xp,  aW_xp,  (long)N_LAYER * 64 * D_INNER);
  cvt(W_dt,  aW_dt,  (long)N_LAYER * D_INNER * DT_RANK);
  cvt(W_out, aW_out, (long)N_LAYER * D_MODEL * D_INNER);
  cvt(W_f1,  aW_f1,  (long)N_LAYER * H_FFN * D_MODEL);
  cvt(W_f2,  aW_f2,  (long)N_LAYER * D_MODEL * H_FFN);
  cvt(lm_w,  aLm,    (long)VOCAB * D_MODEL);

  embed_k<<<BT, 256, 0, stream>>>(idx, tok, pos, x_res, dflag);

  // layer-0 ln1 (subsequent ln1's are fused into the previous layer's
  // FFN2 reduce epilogue)
  ln_k<<<BT, 64, 0, stream>>>(x_res, ln1_g, ln1_b, 0, lnbuf, dflag);

  for (int l = 0; l < N_LAYER; l++) {
    long oWin = (long)l * 2*D_INNER * D_MODEL;
    long oWxp = (long)l * 64 * D_INNER;
    long oWdt = (long)l * D_INNER * DT_RANK;
    long oWo  = (long)l * D_MODEL * D_INNER;
    long oWf1 = (long)l * H_FFN * D_MODEL;
    long oWf2 = (long)l * D_MODEL * H_FFN;
    long oA   = (long)l * D_INNER * D_STATE;
    long oD   = (long)l * D_INNER;

    // W_in: M=2048 N=2048 K=512, BN=64 -> grid 32x16 = 512 blocks (2/CU)
    gemm_nt<0, false, false, 64><<<dim3(2 * D_INNER / 64, BT / 128), 256, 0, stream>>>(
        lnbuf, aW_in + oWin, W_in, oWin, xz, nullptr, 0, nullptr, dflag,
        BT, 2 * D_INNER, D_MODEL, 2 * D_INNER, 0);

    conv_silu_k<<<BT * D_INNER / 256, 256, 0, stream>>>(
        xz, conv_w, conv_b, (long)l * D_INNER * D_CONV, oD, ubuf, dflag);

    xdbl_k<<<BT, 256, 0, stream>>>(ubuf, aW_xp + oWxp, W_xp, oWxp, xdbl, dflag);

    dt_k<<<BT * 4, 256, 0, stream>>>(
        xdbl, aW_dt + oWdt, W_dt, oWdt, b_dt, oD, dtb, dflag);

    scanA_k<<<BATCH * 64 * NCHUNK, 256, 0, stream>>>(
        dtb, ubuf, xdbl, A_log, oA, Pbuf, Qbuf, dflag);
    scanB_k<<<BATCH * D_INNER * D_STATE / 256, 256, 0, stream>>>(Pbuf, Qbuf, Hin);
    scanC_k<<<BATCH * 64 * NCHUNK, 256, 0, stream>>>(
        dtb, ubuf, xdbl, xz, A_log, oA, D_p, oD, Hin, ybuf, dflag);

    // W_out: M=2048 N=512 K=1024 -> split-K x4, BN=64: grid 8x16x4 = 512
    gemm_nt_sk<<<dim3(D_MODEL / 64, BT / 128, KSPLIT), 256, 0, stream>>>(
        ybuf, aW_out + oWo, W_out, oWo, cpart, dflag, BT, D_MODEL, D_INNER);
    // fused: reduce + residual -> x_res; ln2 -> lnbuf
    redk_ln_k<true><<<BT, 64, 0, stream>>>(
        cpart, nullptr, 0, x_res, x_res, ln2_g, ln2_b, (long)l * D_MODEL,
        lnbuf, dflag);

    // FFN1: M=2048 N=2048 K=512, BN=64 -> 512 blocks
    gemm_nt<1, true, false, 64><<<dim3(H_FFN / 64, BT / 128), 256, 0, stream>>>(
        lnbuf, aW_f1 + oWf1, W_f1, oWf1, hbuf, b_f1, (long)l * H_FFN, nullptr, dflag,
        BT, H_FFN, D_MODEL, H_FFN, 0);

    // FFN2: M=2048 N=512 K=2048 -> split-K x4, BN=64
    gemm_nt_sk<<<dim3(D_MODEL / 64, BT / 128, KSPLIT), 256, 0, stream>>>(
        hbuf, aW_f2 + oWf2, W_f2, oWf2, cpart, dflag, BT, D_MODEL, H_FFN);
    // fused: reduce + bias + residual -> x_res; then next ln1 (or final cast)
    if (l + 1 < N_LAYER) {
      redk_ln_k<true><<<BT, 64, 0, stream>>>(
          cpart, b_f2, (long)l * D_MODEL, x_res, x_res,
          ln1_g, ln1_b, (long)(l + 1) * D_MODEL, lnbuf, dflag);
    } else {
      redk_ln_k<false><<<BT, 64, 0, stream>>>(
          cpart, b_f2, (long)l * D_MODEL, x_res, x_res,
          nullptr, nullptr, 0, lnbuf, dflag);
    }
  }

  // logits in two N-halves; SWZ for B-panel L2 reuse.
  for (int h = 0; h < 2; h++) {
    int colbase = h * (VOCAB / 2);
    gemm_nt<2, false, true, 128><<<dim3(VOCAB / 2 / 128, BT / 128), 256, 0, stream>>>(
        lnbuf, aLm + (size_t)colbase * D_MODEL, lm_w, (long)colbase * D_MODEL,
        d_out, lm_b, 0, nullptr, dflag,
        BT, VOCAB / 2, D_MODEL, VOCAB, colbase);
  }
}